// Round 1
// baseline (234.797 us; speedup 1.0000x reference)
//
#include <hip/hip_runtime.h>
#include <math.h>

// Problem constants (match reference setup_inputs)
constexpr int B = 16;
constexpr int N = 4096;
constexpr int D = 512;
constexpr int R = 64;
constexpr int K = 128;

// One 256-thread block per (b, r) pair.
//   Phase 1: scores[k] = dot(x[b, idx[r,k], :], W) + bias   (one wave per row)
//   Phase 2: softmax over K=128 (wave 0)
//   Phase 3: out[b,r,:] = sum_k attn[k] * x[b, idx[r,k], :] (float2 per thread)
__global__ __launch_bounds__(256) void regional_attn_kernel(
    const float* __restrict__ x,     // [B, N, D]
    const int*   __restrict__ idx,   // [R, K]
    const float* __restrict__ W,     // [D]
    const float* __restrict__ bias,  // [1]
    float* __restrict__ out)         // [B, R, D]
{
    const int br   = blockIdx.x;     // 0 .. B*R-1
    const int b    = br / R;
    const int r    = br % R;
    const int tid  = threadIdx.x;
    const int lane = tid & 63;
    const int wave = tid >> 6;       // 0..3

    __shared__ float s_attn[K];      // scores, then attn weights
    __shared__ int   s_idx[K];

    if (tid < K) s_idx[tid] = idx[r * K + tid];
    __syncthreads();

    const float* xb = x + (size_t)b * N * D;

    // ---- Phase 1: scores. One wave per row; lane reads 2 float4 (coalesced). ----
    const float4* W4 = (const float4*)W;
    const float4  w0 = W4[lane];
    const float4  w1 = W4[lane + 64];
    for (int k = wave; k < K; k += 4) {
        const float4* row4 = (const float4*)(xb + (size_t)s_idx[k] * D);
        float4 a0 = row4[lane];
        float4 a1 = row4[lane + 64];
        float p = a0.x * w0.x + a0.y * w0.y + a0.z * w0.z + a0.w * w0.w
                + a1.x * w1.x + a1.y * w1.y + a1.z * w1.z + a1.w * w1.w;
        #pragma unroll
        for (int off = 32; off > 0; off >>= 1)
            p += __shfl_down(p, off, 64);
        if (lane == 0) s_attn[k] = p + bias[0];
    }
    __syncthreads();

    // ---- Phase 2: softmax over 128 (wave 0; 2 elements per lane). ----
    if (wave == 0) {
        float s0 = s_attn[lane];
        float s1 = s_attn[lane + 64];
        float m = fmaxf(s0, s1);
        #pragma unroll
        for (int off = 32; off > 0; off >>= 1)
            m = fmaxf(m, __shfl_down(m, off, 64));
        m = __shfl(m, 0, 64);
        float e0 = __expf(s0 - m);
        float e1 = __expf(s1 - m);
        float s = e0 + e1;
        #pragma unroll
        for (int off = 32; off > 0; off >>= 1)
            s += __shfl_down(s, off, 64);
        s = __shfl(s, 0, 64);
        float inv = 1.0f / s;
        s_attn[lane]      = e0 * inv;
        s_attn[lane + 64] = e1 * inv;
    }
    __syncthreads();

    // ---- Phase 3: weighted sum. Each thread owns float2 at d = 2*tid. ----
    float accx = 0.0f, accy = 0.0f;
    #pragma unroll 4
    for (int k = 0; k < K; ++k) {
        const float2* row2 = (const float2*)(xb + (size_t)s_idx[k] * D);
        float2 v = row2[tid];
        float a = s_attn[k];
        accx = fmaf(a, v.x, accx);
        accy = fmaf(a, v.y, accy);
    }
    float2* out2 = (float2*)(out + ((size_t)b * R + r) * D);
    out2[tid] = make_float2(accx, accy);
}

extern "C" void kernel_launch(void* const* d_in, const int* in_sizes, int n_in,
                              void* d_out, int out_size, void* d_ws, size_t ws_size,
                              hipStream_t stream) {
    const float* x    = (const float*)d_in[0];  // [B,N,D] fp32
    const int*   idx  = (const int*)d_in[1];    // [R,K] int32
    const float* W    = (const float*)d_in[2];  // [1,D] fp32
    const float* bias = (const float*)d_in[3];  // [1] fp32
    float* out = (float*)d_out;                 // [B,R,D] fp32

    dim3 grid(B * R);
    dim3 block(256);
    regional_attn_kernel<<<grid, block, 0, stream>>>(x, idx, W, bias, out);
}

// Round 2
// 200.136 us; speedup vs baseline: 1.1732x; 1.1732x over previous
//
#include <hip/hip_runtime.h>
#include <math.h>

// Problem constants (match reference setup_inputs)
constexpr int B = 16;
constexpr int N = 4096;
constexpr int D = 512;
constexpr int R = 64;
constexpr int K = 128;
constexpr int WAVES = 4;
constexpr int KPW = K / WAVES;   // 32 rows per wave

// One 256-thread block per (b, r). Fused single-pass with per-wave online
// softmax (flash-style): each wave owns 32 rows; each gathered row is read
// from global exactly ONCE (2x float4 per lane), used for both the score
// and the weighted accumulation. 4-wave combine in the epilogue.
// Note: the reference's scalar bias b[0] is added to every score, so it
// cancels in softmax — omitted.
__global__ __launch_bounds__(256) void regional_attn_fused(
    const float* __restrict__ x,     // [B, N, D]
    const int*   __restrict__ idx,   // [R, K]
    const float* __restrict__ W,     // [D]
    float* __restrict__ out)         // [B, R, D]
{
    const int br   = blockIdx.x;     // 0 .. B*R-1
    const int b    = br / R;
    const int r    = br % R;
    const int tid  = threadIdx.x;
    const int lane = tid & 63;
    const int wave = tid >> 6;       // 0..3

    __shared__ int   s_idx[K];
    __shared__ float s_O[WAVES][D];  // 8 KB partial outputs
    __shared__ float s_m[WAVES];
    __shared__ float s_l[WAVES];

    if (tid < K) s_idx[tid] = idx[r * K + tid];

    // W fragment: lane holds D-elements [4*lane, 4*lane+4) and [256+4*lane, ...)
    const float4* W4 = (const float4*)W;
    const float4  w0 = W4[lane];
    const float4  w1 = W4[lane + 64];

    __syncthreads();

    const float* xb = x + (size_t)b * N * D;
    const int kbase = wave * KPW;

    float  m = -INFINITY;
    float  l = 0.0f;
    float4 O0 = make_float4(0.f, 0.f, 0.f, 0.f);
    float4 O1 = make_float4(0.f, 0.f, 0.f, 0.f);

    // software-pipelined: prefetch row kk+1 while processing row kk
    const float4* row = (const float4*)(xb + (size_t)s_idx[kbase] * D);
    float4 a0 = row[lane];
    float4 a1 = row[lane + 64];

    #pragma unroll 2
    for (int kk = 0; kk < KPW; ++kk) {
        float4 b0 = a0, b1 = a1;
        if (kk + 1 < KPW) {
            const float4* nrow = (const float4*)(xb + (size_t)s_idx[kbase + kk + 1] * D);
            a0 = nrow[lane];
            a1 = nrow[lane + 64];
        }
        // score = dot(row, W): 8 partial products per lane, butterfly-reduce
        float p = b0.x * w0.x + b0.y * w0.y + b0.z * w0.z + b0.w * w0.w
                + b1.x * w1.x + b1.y * w1.y + b1.z * w1.z + b1.w * w1.w;
        #pragma unroll
        for (int off = 1; off < 64; off <<= 1)
            p += __shfl_xor(p, off, 64);
        // online softmax update (all lanes hold identical p, m, l, alpha)
        float m_new  = fmaxf(m, p);
        float alpha  = __expf(m - m_new);     // exp(-inf)=0 handles first iter
        float e      = __expf(p - m_new);
        m = m_new;
        l = l * alpha + e;
        O0.x = O0.x * alpha + e * b0.x;
        O0.y = O0.y * alpha + e * b0.y;
        O0.z = O0.z * alpha + e * b0.z;
        O0.w = O0.w * alpha + e * b0.w;
        O1.x = O1.x * alpha + e * b1.x;
        O1.y = O1.y * alpha + e * b1.y;
        O1.z = O1.z * alpha + e * b1.z;
        O1.w = O1.w * alpha + e * b1.w;
    }

    // stash per-wave state
    ((float4*)&s_O[wave][0])[lane]      = O0;
    ((float4*)&s_O[wave][0])[lane + 64] = O1;
    if (lane == 0) { s_m[wave] = m; s_l[wave] = l; }
    __syncthreads();

    // combine 4 waves: out = sum_w O_w * exp(m_w - M) / sum_w l_w * exp(m_w - M)
    const float M  = fmaxf(fmaxf(s_m[0], s_m[1]), fmaxf(s_m[2], s_m[3]));
    const float e0 = __expf(s_m[0] - M);
    const float e1 = __expf(s_m[1] - M);
    const float e2 = __expf(s_m[2] - M);
    const float e3 = __expf(s_m[3] - M);
    const float denom = s_l[0] * e0 + s_l[1] * e1 + s_l[2] * e2 + s_l[3] * e3;
    const float inv = 1.0f / denom;

    const int d = 2 * tid;   // each thread owns 2 output elements
    float ox = s_O[0][d]     * e0 + s_O[1][d]     * e1
             + s_O[2][d]     * e2 + s_O[3][d]     * e3;
    float oy = s_O[0][d + 1] * e0 + s_O[1][d + 1] * e1
             + s_O[2][d + 1] * e2 + s_O[3][d + 1] * e3;

    float2* out2 = (float2*)(out + ((size_t)b * R + r) * D);
    out2[tid] = make_float2(ox * inv, oy * inv);
}

extern "C" void kernel_launch(void* const* d_in, const int* in_sizes, int n_in,
                              void* d_out, int out_size, void* d_ws, size_t ws_size,
                              hipStream_t stream) {
    const float* x    = (const float*)d_in[0];  // [B,N,D] fp32
    const int*   idx  = (const int*)d_in[1];    // [R,K] int32
    const float* W    = (const float*)d_in[2];  // [1,D] fp32
    // d_in[3] = bias, cancels in softmax
    float* out = (float*)d_out;                 // [B,R,D] fp32

    dim3 grid(B * R);
    dim3 block(256);
    regional_attn_fused<<<grid, block, 0, stream>>>(x, idx, W, out);
}

// Round 3
// 195.941 us; speedup vs baseline: 1.1983x; 1.0214x over previous
//
#include <hip/hip_runtime.h>
#include <math.h>

// Problem constants (match reference setup_inputs)
constexpr int B = 16;
constexpr int N = 4096;
constexpr int D = 512;
constexpr int R = 64;
constexpr int K = 128;
constexpr int WAVES = 8;          // 512-thread blocks -> 32 waves/CU at 4 blocks/CU
constexpr int KPW = K / WAVES;    // 16 rows per wave

// One 512-thread block per (b, r). Fused single-pass with per-wave online
// softmax: each wave owns 16 rows; each gathered row is read from global
// exactly once (2x float4 per lane), used for both score and accumulation.
// 8-wave split-softmax combine in the epilogue.
// Bias b[0] is uniform across scores -> cancels in softmax; omitted.
__global__ __launch_bounds__(512, 8) void regional_attn_fused(
    const float* __restrict__ x,     // [B, N, D]
    const int*   __restrict__ idx,   // [R, K]
    const float* __restrict__ W,     // [D]
    float* __restrict__ out)         // [B, R, D]
{
    // XCD swizzle: blocks are dispatched round-robin over 8 XCDs by
    // blockIdx. Map so XCD j gets b in {2j, 2j+1}: shrinks per-XCD L2
    // working set (~31 MB -> ~14 MB) for better hit rate on row reuse.
    const int v    = blockIdx.x;          // 0..1023
    const int xcd  = v & 7;
    const int slot = v >> 3;              // 0..127
    const int b    = xcd * 2 + (slot >> 6);
    const int r    = slot & 63;

    const int tid  = threadIdx.x;
    const int lane = tid & 63;
    const int wave = tid >> 6;            // 0..7

    __shared__ int   s_idx[K];
    __shared__ float s_O[WAVES][D];       // 16 KB partial outputs
    __shared__ float s_m[WAVES];
    __shared__ float s_l[WAVES];

    if (tid < K) s_idx[tid] = idx[r * K + tid];

    // W fragment: lane holds d in [4*lane, 4*lane+4) and [256+4*lane, ...)
    const float4* W4 = (const float4*)W;
    const float4  w0 = W4[lane];
    const float4  w1 = W4[lane + 64];

    __syncthreads();

    const float* xb = x + (size_t)b * N * D;
    const int kbase = wave * KPW;

    float  m = -INFINITY;
    float  l = 0.0f;
    float4 O0 = make_float4(0.f, 0.f, 0.f, 0.f);
    float4 O1 = make_float4(0.f, 0.f, 0.f, 0.f);

    // depth-1 software prefetch: load row kk+1 while processing row kk
    const float4* row = (const float4*)(xb + (size_t)s_idx[kbase] * D);
    float4 a0 = row[lane];
    float4 a1 = row[lane + 64];

    #pragma unroll 2
    for (int kk = 0; kk < KPW; ++kk) {
        float4 b0 = a0, b1 = a1;
        if (kk + 1 < KPW) {
            const float4* nrow = (const float4*)(xb + (size_t)s_idx[kbase + kk + 1] * D);
            a0 = nrow[lane];
            a1 = nrow[lane + 64];
        }
        // score = dot(row, W): 8 partials per lane, butterfly so all lanes get p
        float p = b0.x * w0.x + b0.y * w0.y + b0.z * w0.z + b0.w * w0.w
                + b1.x * w1.x + b1.y * w1.y + b1.z * w1.z + b1.w * w1.w;
        #pragma unroll
        for (int off = 1; off < 64; off <<= 1)
            p += __shfl_xor(p, off, 64);
        // online softmax update (wave-uniform p, m, l, alpha)
        float m_new  = fmaxf(m, p);
        float alpha  = __expf(m - m_new);     // exp(-inf)=0 handles first iter
        float e      = __expf(p - m_new);
        m = m_new;
        l = l * alpha + e;
        O0.x = O0.x * alpha + e * b0.x;
        O0.y = O0.y * alpha + e * b0.y;
        O0.z = O0.z * alpha + e * b0.z;
        O0.w = O0.w * alpha + e * b0.w;
        O1.x = O1.x * alpha + e * b1.x;
        O1.y = O1.y * alpha + e * b1.y;
        O1.z = O1.z * alpha + e * b1.z;
        O1.w = O1.w * alpha + e * b1.w;
    }

    // stash per-wave state
    ((float4*)&s_O[wave][0])[lane]      = O0;
    ((float4*)&s_O[wave][0])[lane + 64] = O1;
    if (lane == 0) { s_m[wave] = m; s_l[wave] = l; }
    __syncthreads();

    // combine 8 waves: out = sum_w O_w*exp(m_w-M) / sum_w l_w*exp(m_w-M)
    float M = s_m[0];
    #pragma unroll
    for (int w = 1; w < WAVES; ++w) M = fmaxf(M, s_m[w]);
    float ew[WAVES];
    float denom = 0.0f;
    #pragma unroll
    for (int w = 0; w < WAVES; ++w) {
        ew[w] = __expf(s_m[w] - M);
        denom += s_l[w] * ew[w];
    }
    const float inv = 1.0f / denom;

    const int d = tid;   // each thread owns one output element
    float o = 0.0f;
    #pragma unroll
    for (int w = 0; w < WAVES; ++w) o += s_O[w][d] * ew[w];

    out[((size_t)b * R + r) * D + d] = o * inv;
}

extern "C" void kernel_launch(void* const* d_in, const int* in_sizes, int n_in,
                              void* d_out, int out_size, void* d_ws, size_t ws_size,
                              hipStream_t stream) {
    const float* x    = (const float*)d_in[0];  // [B,N,D] fp32
    const int*   idx  = (const int*)d_in[1];    // [R,K] int32
    const float* W    = (const float*)d_in[2];  // [1,D] fp32
    // d_in[3] = bias, cancels in softmax
    float* out = (float*)d_out;                 // [B,R,D] fp32

    dim3 grid(B * R);
    dim3 block(512);
    regional_attn_fused<<<grid, block, 0, stream>>>(x, idx, W, out);
}